// Round 1
// baseline (2936.040 us; speedup 1.0000x reference)
//
#include <hip/hip_runtime.h>
#include <stdint.h>

static constexpr int BATCH = 16;
static constexpr int Hh = 1024;
static constexpr int Ww = 1024;
static constexpr int HW = Hh * Ww;        // 2^20
static constexpr int NPIX = BATCH * HW;   // 2^24

// ---------------- union-find helpers (Komura/Playne atomic min-link) -------

__device__ __forceinline__ int find_root(int* parent, int i) {
    int p = parent[i];
    while (p != i) { i = p; p = parent[i]; }
    return i;
}

__device__ __forceinline__ void merge_uf(int* parent, int a, int b) {
    while (true) {
        a = find_root(parent, a);
        b = find_root(parent, b);
        if (a == b) return;
        if (a > b) { int t = a; a = b; b = t; }   // ensure a < b
        int old = atomicMin(&parent[b], a);
        if (old == b) return;   // b was a root and we linked it under a
        b = old;                // parent[b] already changed; keep merging
    }
}

// ---------------- kernels --------------------------------------------------

__global__ __launch_bounds__(256) void k_init(const float* __restrict__ x,
                                              int* __restrict__ parent,
                                              int* __restrict__ counts,
                                              unsigned long long* __restrict__ best) {
    int i = blockIdx.x * blockDim.x + threadIdx.x;
    int b = i >> 20;            // / HW
    int p = i & (HW - 1);
    const float* xb = x + ((size_t)b * 2) * (size_t)HW;
    float x0 = xb[p];
    float x1 = xb[p + HW];
    // argmax over 2 classes, first-index tie-break => fg iff x1 > x0
    parent[i] = (x1 > x0) ? i : -1;
    counts[i] = 0;
    if (i < BATCH) best[i] = 0ull;
}

__global__ __launch_bounds__(256) void k_merge(int* __restrict__ parent) {
    int i = blockIdx.x * blockDim.x + threadIdx.x;
    if (parent[i] < 0) return;      // background
    int p = i & (HW - 1);
    int w = p & (Ww - 1);
    int h = p >> 10;
    // union with the 4 "prior" neighbors: W, NW, N, NE (each edge once)
    if (w > 0 && parent[i - 1] >= 0) merge_uf(parent, i, i - 1);
    if (h > 0) {
        if (parent[i - Ww] >= 0) merge_uf(parent, i, i - Ww);
        if (w > 0 && parent[i - Ww - 1] >= 0) merge_uf(parent, i, i - Ww - 1);
        if (w < Ww - 1 && parent[i - Ww + 1] >= 0) merge_uf(parent, i, i - Ww + 1);
    }
}

__global__ __launch_bounds__(256) void k_compress(int* __restrict__ parent) {
    int i = blockIdx.x * blockDim.x + threadIdx.x;
    if (parent[i] < 0) return;
    parent[i] = find_root(parent, i);
}

// Wave-aggregated counting: one atomic per (wave, distinct root).
// Needed because the giant component would otherwise serialize ~1M atomics
// on a single address per image.
__global__ __launch_bounds__(256) void k_count(const int* __restrict__ parent,
                                               int* __restrict__ counts) {
    int i = blockIdx.x * blockDim.x + threadIdx.x;
    int root = parent[i];
    bool need = (root >= 0);
    int lane = threadIdx.x & 63;
    while (__any(need)) {
        unsigned long long m = __ballot(need);
        int src = (int)(__ffsll(m) - 1);          // uniform across wave
        int r = __shfl(root, src);
        bool mine = need && (root == r);
        unsigned long long grp = __ballot(mine);
        if (mine && lane == src) atomicAdd(&counts[r], (int)__popcll(grp));
        if (mine) need = false;
    }
}

// argmax(count) with smallest-root tie-break, via packed u64 atomicMax:
//   key = (count << 32) | (0xFFFFFFFF - root)
__global__ __launch_bounds__(256) void k_argmax(const int* __restrict__ counts,
                                                unsigned long long* __restrict__ best) {
    int i = blockIdx.x * blockDim.x + threadIdx.x;
    int c = counts[i];
    unsigned long long v = 0ull;
    if (c > 0)
        v = (((unsigned long long)(unsigned)c) << 32) |
            (unsigned long long)(0xFFFFFFFFu - (unsigned)i);
    // wave-level max reduction (64 consecutive i are always in one batch)
    for (int off = 32; off > 0; off >>= 1) {
        unsigned long long o = __shfl_down(v, off);
        if (o > v) v = o;
    }
    if ((threadIdx.x & 63) == 0 && v != 0ull)
        atomicMax(&best[i >> 20], v);
}

__global__ __launch_bounds__(256) void k_final(const float* __restrict__ x,
                                               const int* __restrict__ parent,
                                               const unsigned long long* __restrict__ best,
                                               float* __restrict__ out) {
    int i = blockIdx.x * blockDim.x + threadIdx.x;
    int b = i >> 20;
    int p = i & (HW - 1);
    unsigned long long bv = best[b];
    int broot = (int)(0xFFFFFFFFu - (unsigned)(bv & 0xFFFFFFFFull));
    int pr = parent[i];
    bool mask = (pr >= 0) && (pr == broot);
    const float* xb = x + ((size_t)b * 2) * (size_t)HW;
    float* ob = out + ((size_t)b * 2) * (size_t)HW;
    float x0 = xb[p];
    float x1 = xb[p + HW];
    ob[p]      = mask ? x0 : 0.0f;
    ob[p + HW] = mask ? x1 : 0.0f;
}

// ---------------- launch ---------------------------------------------------

extern "C" void kernel_launch(void* const* d_in, const int* in_sizes, int n_in,
                              void* d_out, int out_size, void* d_ws, size_t ws_size,
                              hipStream_t stream) {
    const float* x = (const float*)d_in[0];
    float* out = (float*)d_out;

    // workspace layout: best[16] u64 | parent[NPIX] i32 | counts[NPIX] i32
    unsigned long long* best = (unsigned long long*)d_ws;
    int* parent = (int*)((char*)d_ws + 256);
    int* counts = parent + NPIX;

    dim3 blk(256);
    dim3 grd(NPIX / 256);   // NPIX is a multiple of 256, no tail

    k_init    <<<grd, blk, 0, stream>>>(x, parent, counts, best);
    k_merge   <<<grd, blk, 0, stream>>>(parent);
    k_compress<<<grd, blk, 0, stream>>>(parent);
    k_count   <<<grd, blk, 0, stream>>>(parent, counts);
    k_argmax  <<<grd, blk, 0, stream>>>(counts, best);
    k_final   <<<grd, blk, 0, stream>>>(x, parent, best, out);
}

// Round 3
// 1770.117 us; speedup vs baseline: 1.6587x; 1.6587x over previous
//
#include <hip/hip_runtime.h>
#include <stdint.h>

static constexpr int BATCH = 16;
static constexpr int Hh = 1024;
static constexpr int Ww = 1024;
static constexpr int HW = Hh * Ww;        // 2^20
static constexpr int NPIX = BATCH * HW;   // 2^24
static constexpr int TS = 32;             // tile side
static constexpr int TPIX = TS * TS;      // 1024 pixels per tile

// ---------------- global union-find (Komura/Playne atomic min-link) --------

// Path-halving find: ONLY safe during the merge phase (k_border), where the
// merge retry loop re-establishes any link displaced by a racing plain store.
__device__ __forceinline__ int find_root_halve(int* parent, int i) {
    while (true) {
        int p = parent[i];
        if (p == i) return i;
        int gp = parent[p];
        if (gp == p) return p;
        parent[i] = gp;        // plain store of an ancestor — merge-phase safe
        i = gp;
    }
}

// Read-only find: used in the compress phase. CRITICAL: compress relies on
// "owner thread's parent[i]=root is the only write to parent[i]"; a halving
// store from another thread could overwrite root with a stale mid-chain
// ancestor AFTER the owner's store (the R1 bug — k_final tests equality).
__device__ __forceinline__ int find_root_ro(const int* parent, int i) {
    int p = parent[i];
    while (p != i) { i = p; p = parent[i]; }
    return i;
}

__device__ __forceinline__ void merge_uf(int* parent, int a, int b) {
    while (true) {
        a = find_root_halve(parent, a);
        b = find_root_halve(parent, b);
        if (a == b) return;
        if (a > b) { int t = a; a = b; b = t; }   // ensure a < b
        int old = atomicMin(&parent[b], a);
        if (old == b) return;   // b was a root and we linked it under a
        b = old;                // someone else linked b first; merge with that
    }
}

// ---------------- K1: per-tile local CCL in LDS ----------------------------
// 32x32 tile, 256 threads, 4 px/thread. Resolves all intra-tile connectivity
// in shared memory, writes tile-rooted labels (depth <= 1) to global parent.

__global__ __launch_bounds__(256) void k_local(const float* __restrict__ x,
                                               int* __restrict__ parent,
                                               int* __restrict__ counts,
                                               unsigned long long* __restrict__ best) {
    __shared__ int lab[TPIX];

    int tile = blockIdx.x;          // 16 images * 1024 tiles
    int b = tile >> 10;
    int t = tile & 1023;
    int th = t >> 5, tw = t & 31;
    int h0 = th * TS, w0 = tw * TS;
    const float* xb = x + (size_t)b * 2 * (size_t)HW;
    int base = b * HW + h0 * Ww + w0;   // global idx of local (0,0)

    if (tile == 0 && threadIdx.x < BATCH) best[threadIdx.x] = 0ull;

    // init local labels from fg = (x1 > x0)
    #pragma unroll
    for (int k = 0; k < 4; k++) {
        int p = threadIdx.x + k * 256;      // local index
        int lh = p >> 5, lw = p & 31;
        int off = (h0 + lh) * Ww + (w0 + lw);
        float x0 = xb[off];
        float x1 = xb[off + HW];
        lab[p] = (x1 > x0) ? p : -1;
        counts[base + lh * Ww + lw] = 0;    // zero counts along the way
    }
    __syncthreads();

    // LDS union-find merge with 4 "prior" neighbors (W, NW, N, NE)
    auto find_l = [&](int i) {
        int p = lab[i];
        while (p != i) { i = p; p = lab[i]; }
        return i;
    };
    auto merge_l = [&](int a, int c) {
        while (true) {
            a = find_l(a); c = find_l(c);
            if (a == c) return;
            if (a > c) { int tt = a; a = c; c = tt; }
            int old = atomicMin(&lab[c], a);
            if (old == c) return;
            c = old;
        }
    };

    #pragma unroll
    for (int k = 0; k < 4; k++) {
        int p = threadIdx.x + k * 256;
        if (lab[p] < 0) continue;
        int lh = p >> 5, lw = p & 31;
        if (lw > 0 && lab[p - 1] >= 0) merge_l(p, p - 1);
        if (lh > 0) {
            if (lab[p - TS] >= 0) merge_l(p, p - TS);
            if (lw > 0 && lab[p - TS - 1] >= 0) merge_l(p, p - TS - 1);
            if (lw < TS - 1 && lab[p - TS + 1] >= 0) merge_l(p, p - TS + 1);
        }
    }
    __syncthreads();

    // flatten + write global labels (local min-index root maps to global
    // min-index root within the tile: (lh,lw) lex order is monotone in g)
    #pragma unroll
    for (int k = 0; k < 4; k++) {
        int p = threadIdx.x + k * 256;
        int lh = p >> 5, lw = p & 31;
        int g = base + lh * Ww + lw;
        int v = lab[p];
        if (v < 0) { parent[g] = -1; continue; }
        int r = find_l(p);
        parent[g] = base + (r >> 5) * Ww + (r & 31);
    }
}

// ---------------- K2: cross-tile border merges -----------------------------

__global__ __launch_bounds__(256) void k_border(int* __restrict__ parent) {
    int i = blockIdx.x * blockDim.x + threadIdx.x;
    int p = i & (HW - 1);
    int w = p & (Ww - 1);
    int h = p >> 10;
    bool hb = (h & 31) == 0;          // N/NW/NE cross the top tile edge
    bool wb = (w & 31) == 0;          // W/NW cross the left tile edge
    bool we = (w & 31) == 31;         // NE crosses the right tile edge
    if (!(hb | wb | we)) return;
    if (parent[i] < 0) return;
    if (wb && w > 0 && parent[i - 1] >= 0) merge_uf(parent, i, i - 1);
    if (h > 0) {
        if (hb && parent[i - Ww] >= 0) merge_uf(parent, i, i - Ww);
        if ((hb | wb) && w > 0 && parent[i - Ww - 1] >= 0) merge_uf(parent, i, i - Ww - 1);
        if ((hb | we) && w < Ww - 1 && parent[i - Ww + 1] >= 0) merge_uf(parent, i, i - Ww + 1);
    }
}

// ---------------- K3: compress + wave-aggregated count ---------------------

__global__ __launch_bounds__(256) void k_compress_count(int* __restrict__ parent,
                                                        int* __restrict__ counts) {
    int i = blockIdx.x * blockDim.x + threadIdx.x;
    int pr = parent[i];
    bool need = (pr >= 0);
    int root = -1;
    if (need) {
        root = find_root_ro(parent, i);   // read-only walk (see note above)
        parent[i] = root;                 // sole write to parent[i]
    }
    // wave-aggregated atomicAdd: one atomic per (wave, distinct root);
    // without this the giant component serializes ~1M atomics on one address
    int lane = threadIdx.x & 63;
    while (__any(need)) {
        unsigned long long m = __ballot(need);
        int src = (int)(__ffsll(m) - 1);
        int r = __shfl(root, src);
        bool mine = need && (root == r);
        unsigned long long grp = __ballot(mine);
        if (mine && lane == src) atomicAdd(&counts[r], (int)__popcll(grp));
        if (mine) need = false;
    }
}

// ---------------- K4: argmax(count), smallest-root tie-break ---------------

__global__ __launch_bounds__(256) void k_argmax(const int* __restrict__ counts,
                                                unsigned long long* __restrict__ best) {
    int i = blockIdx.x * blockDim.x + threadIdx.x;
    int c = counts[i];
    unsigned long long v = 0ull;
    if (c > 0)
        v = (((unsigned long long)(unsigned)c) << 32) |
            (unsigned long long)(0xFFFFFFFFu - (unsigned)i);
    for (int off = 32; off > 0; off >>= 1) {
        unsigned long long o = __shfl_down(v, off);
        if (o > v) v = o;
    }
    if ((threadIdx.x & 63) == 0 && v != 0ull)
        atomicMax(&best[i >> 20], v);
}

// ---------------- K5: apply mask -------------------------------------------

__global__ __launch_bounds__(256) void k_final(const float* __restrict__ x,
                                               const int* __restrict__ parent,
                                               const unsigned long long* __restrict__ best,
                                               float* __restrict__ out) {
    int i = blockIdx.x * blockDim.x + threadIdx.x;
    int b = i >> 20;
    int p = i & (HW - 1);
    unsigned long long bv = best[b];
    int broot = (int)(0xFFFFFFFFu - (unsigned)(bv & 0xFFFFFFFFull));
    int pr = parent[i];
    bool mask = (pr >= 0) && (pr == broot);
    const float* xb = x + ((size_t)b * 2) * (size_t)HW;
    float* ob = out + ((size_t)b * 2) * (size_t)HW;
    float x0 = xb[p];
    float x1 = xb[p + HW];
    ob[p]      = mask ? x0 : 0.0f;
    ob[p + HW] = mask ? x1 : 0.0f;
}

// ---------------- launch ---------------------------------------------------

extern "C" void kernel_launch(void* const* d_in, const int* in_sizes, int n_in,
                              void* d_out, int out_size, void* d_ws, size_t ws_size,
                              hipStream_t stream) {
    const float* x = (const float*)d_in[0];
    float* out = (float*)d_out;

    // workspace layout: best[16] u64 (256B pad) | parent[NPIX] i32 | counts[NPIX] i32
    unsigned long long* best = (unsigned long long*)d_ws;
    int* parent = (int*)((char*)d_ws + 256);
    int* counts = parent + NPIX;

    dim3 blk(256);
    dim3 grd(NPIX / 256);
    dim3 grd_tiles(BATCH * (Hh / TS) * (Ww / TS));   // 16384 tiles

    k_local          <<<grd_tiles, blk, 0, stream>>>(x, parent, counts, best);
    k_border         <<<grd, blk, 0, stream>>>(parent);
    k_compress_count <<<grd, blk, 0, stream>>>(parent, counts);
    k_argmax         <<<grd, blk, 0, stream>>>(counts, best);
    k_final          <<<grd, blk, 0, stream>>>(x, parent, best, out);
}